// Round 12
// baseline (1542.049 us; speedup 1.0000x reference)
//
#include <hip/hip_runtime.h>
#include <hip/hip_bf16.h>
#include <math.h>
#include <stdint.h>

using bf16 = __hip_bfloat16;
typedef short bf16x8 __attribute__((ext_vector_type(8)));
typedef float f32x4 __attribute__((ext_vector_type(4)));

__device__ __forceinline__ ushort f2bu(float v){ union{ bf16 h; ushort u; } c; c.h = __float2bfloat16(v); return c.u; }
__device__ __forceinline__ float bu2f(ushort u){ union{ ushort u; bf16 h; } c; c.u = u; return __bfloat162float(c.h); }

__device__ __forceinline__ float gelu_exact(float x){
  return 0.5f * x * (1.0f + erff(x * 0.7071067811865475f));
}
__device__ __forceinline__ float sigmoidf_(float x){ return 1.0f / (1.0f + expf(-x)); }

// ---------------- threefry2x32 (JAX-compatible, verified round 1) ----------------
__device__ __forceinline__ uint32_t rotl32(uint32_t x, int d){ return (x << d) | (x >> (32 - d)); }
__device__ __forceinline__ void threefry2x32(uint32_t k0, uint32_t k1, uint32_t& x0, uint32_t& x1){
  uint32_t ks2 = k0 ^ k1 ^ 0x1BD11BDAu;
  x0 += k0; x1 += k1;
#define TF_R(r) { x0 += x1; x1 = rotl32(x1, r); x1 ^= x0; }
  TF_R(13) TF_R(15) TF_R(26) TF_R(6)  x0 += k1;  x1 += ks2 + 1u;
  TF_R(17) TF_R(29) TF_R(16) TF_R(24) x0 += ks2; x1 += k0 + 2u;
  TF_R(13) TF_R(15) TF_R(26) TF_R(6)  x0 += k0;  x1 += k1 + 3u;
  TF_R(17) TF_R(29) TF_R(16) TF_R(24) x0 += k1;  x1 += ks2 + 4u;
  TF_R(13) TF_R(15) TF_R(26) TF_R(6)  x0 += ks2; x1 += k0 + 5u;
#undef TF_R
}

__device__ __forceinline__ float erfinv_f(float x){
  float w = -log1pf(-x * x);
  float p;
  if (w < 5.0f){
    w -= 2.5f;
    p = 2.81022636e-08f;
    p = fmaf(p, w, 3.43273939e-07f);
    p = fmaf(p, w, -3.5233877e-06f);
    p = fmaf(p, w, -4.39150654e-06f);
    p = fmaf(p, w, 0.00021858087f);
    p = fmaf(p, w, -0.00125372503f);
    p = fmaf(p, w, -0.00417768164f);
    p = fmaf(p, w, 0.246640727f);
    p = fmaf(p, w, 1.50140941f);
  } else {
    w = sqrtf(w) - 3.0f;
    p = -0.000200214257f;
    p = fmaf(p, w, 0.000100950558f);
    p = fmaf(p, w, 0.00134934322f);
    p = fmaf(p, w, -0.00367342844f);
    p = fmaf(p, w, 0.00573950773f);
    p = fmaf(p, w, -0.0076224613f);
    p = fmaf(p, w, 0.00943887047f);
    p = fmaf(p, w, 1.00167406f);
    p = fmaf(p, w, 2.83297682f);
  }
  return p * x;
}

// ---------------- weight prep: [COUT][CIN][3][3] f32 -> bf16 [co][KP], k = tap*CIN+ci, linear ----------------
__global__ void prep_w(const float* __restrict__ w, ushort* __restrict__ dst, int CIN, int COUT, int KP){
  int idx = blockIdx.x * 256 + threadIdx.x;
  if (idx >= COUT * KP) return;
  int co = idx / KP, kl = idx % KP;
  int KT = 9 * CIN;
  ushort v = 0;
  if (kl < KT){
    int tap = kl / CIN, ci = kl % CIN;
    v = f2bu(w[(co * CIN + ci) * 9 + tap]);
  }
  dst[idx] = v;
}

// fc weight f32 -> bf16, linear [256][4096]
__global__ void prep_fcb(const float* __restrict__ w, ushort* __restrict__ wb){
  int idx = blockIdx.x * 256 + threadIdx.x;
  if (idx >= 256 * 4096) return;
  wb[idx] = f2bu(w[idx]);
}

// LSTM weights: Wcat[l][j][0..127]=bf16(Wih[l][j][:]), [128..255]=bf16(Whh[l][j][:]); bsum[l][j]
__global__ void prep_lstm_cat(const float* __restrict__ Wih, const float* __restrict__ Whh,
                              const float* __restrict__ bih, const float* __restrict__ bhh,
                              ushort* __restrict__ Wcat, float* __restrict__ bsum){
  int idx = blockIdx.x * 256 + threadIdx.x;            // 5*512*128 = 327680
  if (idx < 327680){
    int k = idx & 127, j = (idx >> 7) & 511, l = idx >> 16;
    Wcat[(size_t)(l * 512 + j) * 256 + k]       = f2bu(Wih[idx]);
    Wcat[(size_t)(l * 512 + j) * 256 + 128 + k] = f2bu(Whh[idx]);
  }
  if (idx < 2560) bsum[idx] = bih[idx] + bhh[idx];
}

// ---------------- conv1: 1->32ch, stride 2, channels-last bf16 out, coalesced uint4 stores ----------------
__global__ __launch_bounds__(256) void conv1_gelu(const float* __restrict__ x, const float* __restrict__ w,
                                                  const float* __restrict__ b, ushort* __restrict__ out){
  __shared__ float sw[288];
  __shared__ float sb[32];
  int tid = threadIdx.x;
  if (tid < 288) sw[tid] = w[tid];
  if (tid < 32)  sb[tid] = b[tid];
  __syncthreads();
  int pl = tid >> 2, q = tid & 3;
  int gp = blockIdx.x * 64 + pl;
  int n = gp >> 10, p = gp & 1023;
  int oy = p >> 5, ox = p & 31;
  const float* xim = x + (size_t)n * 4096;
  float patch[9];
#pragma unroll
  for (int dy = 0; dy < 3; ++dy)
#pragma unroll
    for (int dx = 0; dx < 3; ++dx){
      int iy = oy * 2 + dy - 1, ix = ox * 2 + dx - 1;
      bool ok = ((unsigned)iy < 64u) && ((unsigned)ix < 64u);
      patch[dy * 3 + dx] = ok ? xim[iy * 64 + ix] : 0.f;
    }
  __align__(16) ushort res[8];
#pragma unroll
  for (int j = 0; j < 8; ++j){
    int co = q * 8 + j;
    float a = sb[co];
#pragma unroll
    for (int t = 0; t < 9; ++t) a = fmaf(patch[t], sw[co * 9 + t], a);
    res[j] = f2bu(gelu_exact(a));
  }
  *(uint4*)(out + (size_t)gp * 32 + q * 8) = *(const uint4*)res;
}

// ---------------- implicit-GEMM MFMA conv (3x3, pad 1), channels-last, padded LDS ----------------
template<int CIN, int COUT, int HOUT, int WOUT, int S, int WAVES, bool NCHW_OUT>
__global__ __launch_bounds__(WAVES * 64) void conv_mfma(const ushort* __restrict__ in, const ushort* __restrict__ wt,
                                                        const float* __restrict__ bias, ushort* __restrict__ out){
  constexpr int HIN = HOUT * S, WIN = WOUT * S;
  constexpr int KT = 9 * CIN;
  constexpr int KP = (CIN == 32) ? 296 : 600;
  constexpr int CP = CIN + 8;
  constexpr int PIN = HIN * WIN;
  constexpr int POUT = HOUT * WOUT;
  constexpr int MT = POUT / 16, NT = COUT / 16, MTW = MT / WAVES;
  constexpr int NTH = WAVES * 64;
  constexpr int KS = KT / 32;
  __shared__ __align__(16) ushort sIn[PIN * CP];
  __shared__ __align__(16) ushort sW[COUT * KP];
  int tid = threadIdx.x;

  const ushort* gin = in + (size_t)blockIdx.x * PIN * CIN;
  for (int t = tid; t < PIN * CIN / 8; t += NTH){
    int e = t * 8;
    int ci = e & (CIN - 1);
    int pix = e / CIN;
    *(uint4*)&sIn[pix * CP + ci] = *(const uint4*)(gin + e);
  }
  for (int t = tid; t < COUT * KP / 8; t += NTH)
    *(uint4*)&sW[t * 8] = *(const uint4*)(wt + t * 8);
  __syncthreads();

  int wid = tid >> 6, lane = tid & 63;
  int l15 = lane & 15, lg = lane >> 4;

  int iyb[MTW], ixb[MTW];
#pragma unroll
  for (int m = 0; m < MTW; ++m){
    int mt = m * WAVES + wid;
    int p = mt * 16 + l15;
    iyb[m] = (p / WOUT) * S - 1;
    ixb[m] = (p % WOUT) * S - 1;
  }
  f32x4 acc[MTW][NT] = {};
  float bv[NT];
#pragma unroll
  for (int nt = 0; nt < NT; ++nt) bv[nt] = bias[nt * 16 + l15];

  const bf16x8 ZV = {0,0,0,0,0,0,0,0};
#pragma unroll
  for (int ks = 0; ks < KS; ++ks){
    int tap = (ks * 32) / CIN;
    int dy = tap / 3, dx = tap % 3;
    int cib = (ks * 32) % CIN + lg * 8;
    bf16x8 bfr[NT];
#pragma unroll
    for (int nt = 0; nt < NT; ++nt){
      int co = nt * 16 + l15;
      bfr[nt] = *(const bf16x8*)&sW[co * KP + ks * 32 + lg * 8];
    }
#pragma unroll
    for (int m = 0; m < MTW; ++m){
      int iy = iyb[m] + dy, ix = ixb[m] + dx;
      bool ok = ((unsigned)iy < (unsigned)HIN) && ((unsigned)ix < (unsigned)WIN);
      int pixi = ok ? (iy * WIN + ix) : 0;
      bf16x8 a = *(const bf16x8*)&sIn[pixi * CP + cib];
      if (!ok) a = ZV;
#pragma unroll
      for (int nt = 0; nt < NT; ++nt)
        acc[m][nt] = __builtin_amdgcn_mfma_f32_16x16x32_bf16(a, bfr[nt], acc[m][nt], 0, 0, 0);
    }
  }

  if constexpr (!NCHW_OUT){
    constexpr int RG = 16 * WAVES;
    __shared__ ushort sOut[RG * COUT];
    size_t obase = (size_t)blockIdx.x * POUT * COUT;
#pragma unroll
    for (int m = 0; m < MTW; ++m){
      if (m) __syncthreads();
#pragma unroll
      for (int nt = 0; nt < NT; ++nt){
        int co = nt * 16 + l15;
#pragma unroll
        for (int r = 0; r < 4; ++r){
          int rl = wid * 16 + lg * 4 + r;
          sOut[rl * COUT + co] = f2bu(gelu_exact(acc[m][nt][r] + bv[nt]));
        }
      }
      __syncthreads();
      for (int t = tid; t < RG * COUT / 8; t += NTH)
        *(uint4*)(out + obase + (size_t)m * RG * COUT + t * 8) = *(const uint4*)&sOut[t * 8];
    }
  } else {
#pragma unroll
    for (int m = 0; m < MTW; ++m){
      int mt = m * WAVES + wid;
#pragma unroll
      for (int nt = 0; nt < NT; ++nt){
        int co = nt * 16 + l15;
#pragma unroll
        for (int r = 0; r < 4; ++r){
          int prow = mt * 16 + lg * 4 + r;
          float v = gelu_exact(acc[m][nt][r] + bv[nt]);
          out[(size_t)blockIdx.x * POUT * COUT + co * POUT + prow] = f2bu(v);
        }
      }
    }
  }
}

// ---------------- encoder FC, split-K MFMA: partial[sl][1040][256] (verified round 8) ----------------
__global__ __launch_bounds__(256) void fc_mfma_sk(const ushort* __restrict__ A, const ushort* __restrict__ Wb,
                                                  float* __restrict__ partial){
  __shared__ __align__(16) ushort sA[64][72];
  __shared__ __align__(16) ushort sB[256][72];
  int tid = threadIdx.x;
  int mt = blockIdx.x >> 3, sl = blockIdx.x & 7;
  int M0 = mt * 64;
  int wid = tid >> 6, lane = tid & 63;
  int l15 = lane & 15, lg = lane >> 4;

  f32x4 acc[16] = {};
  for (int i8 = 0; i8 < 8; ++i8){
    int kb = sl * 8 + i8;
#pragma unroll
    for (int i = 0; i < 2; ++i){
      int t = i * 256 + tid;
      int row = t >> 3, c = t & 7;
      int grow = M0 + row; if (grow > 1039) grow = 1039;
      *(uint4*)&sA[row][c * 8] = *(const uint4*)(A + (size_t)grow * 4096 + kb * 64 + c * 8);
    }
#pragma unroll
    for (int i = 0; i < 8; ++i){
      int t = i * 256 + tid;
      int row = t >> 3, c = t & 7;
      *(uint4*)&sB[row][c * 8] = *(const uint4*)(Wb + (size_t)row * 4096 + kb * 64 + c * 8);
    }
    __syncthreads();
#pragma unroll
    for (int ks = 0; ks < 2; ++ks){
      bf16x8 a = *(const bf16x8*)&sA[wid * 16 + l15][ks * 32 + lg * 8];
#pragma unroll
      for (int nt = 0; nt < 16; ++nt){
        bf16x8 b = *(const bf16x8*)&sB[nt * 16 + l15][ks * 32 + lg * 8];
        acc[nt] = __builtin_amdgcn_mfma_f32_16x16x32_bf16(a, b, acc[nt], 0, 0, 0);
      }
    }
    __syncthreads();
  }
#pragma unroll
  for (int nt = 0; nt < 16; ++nt){
    int j = nt * 16 + l15;
#pragma unroll
    for (int r = 0; r < 4; ++r){
      int row = M0 + wid * 16 + lg * 4 + r;
      if (row < 1040) partial[((size_t)sl * 1040 + row) * 256 + j] = acc[nt][r];
    }
  }
}

__global__ void fc_reduce(const float* __restrict__ partial, const float* __restrict__ fcb,
                          float* __restrict__ ml){
  int idx = blockIdx.x * 256 + threadIdx.x;
  if (idx >= 266240) return;
  float s = fcb[idx & 255];
#pragma unroll
  for (int q = 0; q < 8; ++q) s += partial[(size_t)q * 266240 + idx];
  ml[idx] = s;
}

// ---------------- reparameterization (+ f32 z relaid to [t*16+b][128]) ----------------
__global__ void reparam_kernel(const float* __restrict__ ml, float* __restrict__ z,
                               float* __restrict__ zre){
  int i = blockIdx.x * 256 + threadIdx.x;
  if (i >= 133120) return;
  uint32_t x0 = 0u, x1 = (uint32_t)i;
  threefry2x32(0u, 42u, x0, x1);
  uint32_t bits = x0 ^ x1;
  uint32_t fb = (bits >> 9) | 0x3f800000u;
  float f = __uint_as_float(fb) - 1.0f;
  const float lo = -0.99999994f;
  float u = f * 2.0f + lo;
  u = fmaxf(lo, u);
  float eps = 1.41421354f * erfinv_f(u);
  int n = i >> 7, d = i & 127;
  float ex = expf(fminf(0.5f * ml[n * 256 + 128 + d], 60.0f));
  float zv = fmaf(eps, ex, ml[n * 256 + d]);
  z[i] = zv;
  int b = n / 65, t = n - b * 65;
  if (t < 64) zre[((size_t)t * 16 + b) * 128 + d] = zv;
}

// ---------------- LSTM layer: 16 blocks (1 batch each), 512 thr (1 gate-row j each) ----------------
// Bit-identical math to round-7's verified lstm_wave: f32 x/h/c, bf16 weights, same
// k-ascending fmaf(x,wih,fmaf(h,whh,a)) chain, same gate formulas. W rows cached in VGPRs.
__global__ __launch_bounds__(512) void lstm_layer(const float* __restrict__ xin,   // [t*16+b][128] f32
                                                  const ushort* __restrict__ Wcat, // [512][256] bf16 (ih|hh)
                                                  const float* __restrict__ bsum,  // [512]
                                                  float* __restrict__ hout){       // [t*16+b][128] f32
  int b = blockIdx.x;
  int tid = threadIdx.x;
  __shared__ __align__(16) float sX[128], sH[128];
  __shared__ float gts[512];

  uint32_t wih[64], whh[64];
  {
    const uint4* wp = (const uint4*)(Wcat + (size_t)tid * 256);
#pragma unroll
    for (int i = 0; i < 16; ++i){
      uint4 v = wp[i];
      wih[i*4+0] = v.x; wih[i*4+1] = v.y; wih[i*4+2] = v.z; wih[i*4+3] = v.w;
    }
#pragma unroll
    for (int i = 0; i < 16; ++i){
      uint4 v = wp[16 + i];
      whh[i*4+0] = v.x; whh[i*4+1] = v.y; whh[i*4+2] = v.z; whh[i*4+3] = v.w;
    }
  }
  float bs = bsum[tid];
  float c = 0.f;
  float xnext = 0.f;
  if (tid < 128){
    sH[tid] = 0.f;
    sX[tid] = xin[(size_t)b * 128 + tid];               // t = 0
  }
  __syncthreads();

  for (int t = 0; t < 64; ++t){
    if (tid < 128 && t < 63) xnext = xin[((size_t)(t + 1) * 16 + b) * 128 + tid]; // prefetch
    float a = bs;
#pragma unroll
    for (int kc = 0; kc < 8; ++kc){
      f32x4 xv[4], hv[4];
#pragma unroll
      for (int q = 0; q < 4; ++q){
        xv[q] = *(const f32x4*)&sX[kc * 16 + q * 4];
        hv[q] = *(const f32x4*)&sH[kc * 16 + q * 4];
      }
#pragma unroll
      for (int q = 0; q < 8; ++q){                       // k = kc*16 + 2q, 2q+1 (ascending)
        uint32_t wi = wih[kc * 8 + q], wh = whh[kc * 8 + q];
        float wie = __uint_as_float(wi << 16);
        float wio = __uint_as_float(wi & 0xffff0000u);
        float whe = __uint_as_float(wh << 16);
        float who = __uint_as_float(wh & 0xffff0000u);
        float xe = xv[q >> 1][(q & 1) * 2],  xo = xv[q >> 1][(q & 1) * 2 + 1];
        float he = hv[q >> 1][(q & 1) * 2],  ho = hv[q >> 1][(q & 1) * 2 + 1];
        a = fmaf(xe, wie, fmaf(he, whe, a));
        a = fmaf(xo, wio, fmaf(ho, who, a));
      }
    }
    gts[tid] = a;
    __syncthreads();                                     // B: gts ready; k-loop reads done
    if (tid < 128){
      float gi = gts[tid], gf = gts[128 + tid], gg = gts[256 + tid], go = gts[384 + tid];
      float cn = sigmoidf_(gf) * c + sigmoidf_(gi) * tanhf(gg);
      float hn = sigmoidf_(go) * tanhf(cn);
      c = cn;
      sH[tid] = hn;
      hout[((size_t)t * 16 + b) * 128 + tid] = hn;
      if (t < 63) sX[tid] = xnext;
    }
    __syncthreads();                                     // A: sX/sH ready for next step
  }
}

// ---------------- projection + MSE ----------------
__global__ void pred_loss(const float* __restrict__ hbuf, const float* __restrict__ lin_w,
                          const float* __restrict__ lin_b, const float* __restrict__ z,
                          float* __restrict__ partial){
  int blk = blockIdx.x;                                // 16*61
  int b = blk / 61, i = 3 + blk % 61;
  int tid = threadIdx.x;                               // 128
  __shared__ float h5[128];
  h5[tid] = hbuf[((size_t)(4 * 64 + i) * 16 + b) * 128 + tid];
  __syncthreads();
  float acc = lin_b[tid];
  const float* wr = lin_w + tid * 128;
#pragma unroll 8
  for (int k = 0; k < 128; ++k) acc = fmaf(h5[k], wr[k], acc);
  float zy = z[(b * 65 + i + 1) * 128 + tid];
  float df = acc - zy;
  float v = df * df;
  for (int off = 32; off > 0; off >>= 1) v += __shfl_down(v, off);
  __shared__ float wsum[2];
  if ((tid & 63) == 0) wsum[tid >> 6] = v;
  __syncthreads();
  if (tid == 0) partial[blk] = wsum[0] + wsum[1];
}

__global__ void loss_final(const float* __restrict__ partial, float* __restrict__ out){
  int tid = threadIdx.x;                               // 256
  float v = 0.0f;
  for (int i = tid; i < 976; i += 256) v += partial[i];
  for (int off = 32; off > 0; off >>= 1) v += __shfl_down(v, off);
  __shared__ float s[4];
  if ((tid & 63) == 0) s[tid >> 6] = v;
  __syncthreads();
  if (tid == 0) out[0] = (s[0] + s[1] + s[2] + s[3]) * (1.0f / 124928.0f);
}

extern "C" void kernel_launch(void* const* d_in, const int* in_sizes, int n_in,
                              void* d_out, int out_size, void* d_ws, size_t ws_size,
                              hipStream_t stream){
  const float* x   = (const float*)d_in[0];
  const float* ew1 = (const float*)d_in[1];  const float* eb1 = (const float*)d_in[2];
  const float* ew2 = (const float*)d_in[3];  const float* eb2 = (const float*)d_in[4];
  const float* ew3 = (const float*)d_in[5];  const float* eb3 = (const float*)d_in[6];
  const float* ew4 = (const float*)d_in[7];  const float* eb4 = (const float*)d_in[8];
  const float* ew5 = (const float*)d_in[9];  const float* eb5 = (const float*)d_in[10];
  const float* fcw = (const float*)d_in[11]; const float* fcb = (const float*)d_in[12];
  // d_in[13..24]: decoder params (dead code in the reference) — unused
  const float* Wih = (const float*)d_in[25]; const float* Whh = (const float*)d_in[26];
  const float* bih = (const float*)d_in[27]; const float* bhh = (const float*)d_in[28];
  const float* lw  = (const float*)d_in[29]; const float* lb  = (const float*)d_in[30];

  char* ws = (char*)d_ws;
  size_t off = 0;
  auto alloc = [&](size_t bytes) -> void* {
    void* p = ws + off;
    off = (off + bytes + 255) & ~(size_t)255;
    return p;
  };
  ushort* bufA  = (ushort*)alloc(34078720ull * 2);     // 1040*1024*32 bf16
  ushort* bufB  = (ushort*)alloc(34078720ull * 2);
  ushort* wt2   = (ushort*)alloc(32ull * 296 * 2);
  ushort* wt3   = (ushort*)alloc(64ull * 296 * 2);
  ushort* wt4   = (ushort*)alloc(64ull * 600 * 2);
  ushort* wt5   = (ushort*)alloc(64ull * 600 * 2);
  ushort* fcwB  = (ushort*)alloc(256ull * 4096 * 2);
  ushort* Wcat  = (ushort*)alloc(5ull * 512 * 256 * 2);
  float*  bsum  = (float*) alloc(5ull * 512 * 4);
  float*  ml    = (float*) alloc(1040ull * 256 * 4);
  float*  zbuf  = (float*) alloc(1040ull * 128 * 4);
  float*  zre   = (float*) alloc(1024ull * 128 * 4);
  float*  hbuf  = (float*) alloc(5ull * 1024 * 128 * 4);
  float*  part  = (float*) alloc(976ull * 4);
  float*  fpart = (float*)bufB;                        // fc split-K partials reuse dead bufB

  prep_w<<<(32 * 296 + 255) / 256, 256, 0, stream>>>(ew2, wt2, 32, 32, 296);
  prep_w<<<(64 * 296 + 255) / 256, 256, 0, stream>>>(ew3, wt3, 32, 64, 296);
  prep_w<<<(64 * 600 + 255) / 256, 256, 0, stream>>>(ew4, wt4, 64, 64, 600);
  prep_w<<<(64 * 600 + 255) / 256, 256, 0, stream>>>(ew5, wt5, 64, 64, 600);
  prep_fcb<<<4096, 256, 0, stream>>>(fcw, fcwB);
  prep_lstm_cat<<<1280, 256, 0, stream>>>(Wih, Whh, bih, bhh, Wcat, bsum);

  conv1_gelu<<<16640, 256, 0, stream>>>(x, ew1, eb1, bufA);
  conv_mfma<32, 32, 32, 32, 1, 8, false><<<1040, 512, 0, stream>>>(bufA, wt2, eb2, bufB);
  conv_mfma<32, 64, 16, 16, 2, 8, false><<<1040, 512, 0, stream>>>(bufB, wt3, eb3, bufA);
  conv_mfma<64, 64, 16, 16, 1, 8, false><<<1040, 512, 0, stream>>>(bufA, wt4, eb4, bufB);
  conv_mfma<64, 64,  8,  8, 2, 4, true ><<<1040, 256, 0, stream>>>(bufB, wt5, eb5, bufA);

  fc_mfma_sk<<<136, 256, 0, stream>>>(bufA, fcwB, fpart);
  fc_reduce<<<1040, 256, 0, stream>>>(fpart, fcb, ml);
  reparam_kernel<<<(133120 + 255) / 256, 256, 0, stream>>>(ml, zbuf, zre);

  for (int l = 0; l < 5; ++l){
    const float* xin = (l == 0) ? zre : (hbuf + (size_t)(l - 1) * 131072);
    lstm_layer<<<16, 512, 0, stream>>>(xin, Wcat + (size_t)l * 512 * 256, bsum + l * 512,
                                       hbuf + (size_t)l * 131072);
  }

  pred_loss<<<976, 128, 0, stream>>>(hbuf, lw, lb, zbuf, part);
  loss_final<<<1, 256, 0, stream>>>(part, (float*)d_out);
}

// Round 13
// 730.348 us; speedup vs baseline: 2.1114x; 2.1114x over previous
//
#include <hip/hip_runtime.h>
#include <hip/hip_bf16.h>
#include <math.h>
#include <stdint.h>

using bf16 = __hip_bfloat16;
typedef short bf16x8 __attribute__((ext_vector_type(8)));
typedef float f32x4 __attribute__((ext_vector_type(4)));

__device__ __forceinline__ ushort f2bu(float v){ union{ bf16 h; ushort u; } c; c.h = __float2bfloat16(v); return c.u; }
__device__ __forceinline__ float bu2f(ushort u){ union{ ushort u; bf16 h; } c; c.u = u; return __bfloat162float(c.h); }

__device__ __forceinline__ float gelu_exact(float x){
  return 0.5f * x * (1.0f + erff(x * 0.7071067811865475f));
}
__device__ __forceinline__ float sigmoidf_(float x){ return 1.0f / (1.0f + expf(-x)); }

// ---------------- threefry2x32 (JAX-compatible, verified round 1) ----------------
__device__ __forceinline__ uint32_t rotl32(uint32_t x, int d){ return (x << d) | (x >> (32 - d)); }
__device__ __forceinline__ void threefry2x32(uint32_t k0, uint32_t k1, uint32_t& x0, uint32_t& x1){
  uint32_t ks2 = k0 ^ k1 ^ 0x1BD11BDAu;
  x0 += k0; x1 += k1;
#define TF_R(r) { x0 += x1; x1 = rotl32(x1, r); x1 ^= x0; }
  TF_R(13) TF_R(15) TF_R(26) TF_R(6)  x0 += k1;  x1 += ks2 + 1u;
  TF_R(17) TF_R(29) TF_R(16) TF_R(24) x0 += ks2; x1 += k0 + 2u;
  TF_R(13) TF_R(15) TF_R(26) TF_R(6)  x0 += k0;  x1 += k1 + 3u;
  TF_R(17) TF_R(29) TF_R(16) TF_R(24) x0 += k1;  x1 += ks2 + 4u;
  TF_R(13) TF_R(15) TF_R(26) TF_R(6)  x0 += ks2; x1 += k0 + 5u;
#undef TF_R
}

__device__ __forceinline__ float erfinv_f(float x){
  float w = -log1pf(-x * x);
  float p;
  if (w < 5.0f){
    w -= 2.5f;
    p = 2.81022636e-08f;
    p = fmaf(p, w, 3.43273939e-07f);
    p = fmaf(p, w, -3.5233877e-06f);
    p = fmaf(p, w, -4.39150654e-06f);
    p = fmaf(p, w, 0.00021858087f);
    p = fmaf(p, w, -0.00125372503f);
    p = fmaf(p, w, -0.00417768164f);
    p = fmaf(p, w, 0.246640727f);
    p = fmaf(p, w, 1.50140941f);
  } else {
    w = sqrtf(w) - 3.0f;
    p = -0.000200214257f;
    p = fmaf(p, w, 0.000100950558f);
    p = fmaf(p, w, 0.00134934322f);
    p = fmaf(p, w, -0.00367342844f);
    p = fmaf(p, w, 0.00573950773f);
    p = fmaf(p, w, -0.0076224613f);
    p = fmaf(p, w, 0.00943887047f);
    p = fmaf(p, w, 1.00167406f);
    p = fmaf(p, w, 2.83297682f);
  }
  return p * x;
}

// ---------------- weight prep: [COUT][CIN][3][3] f32 -> bf16 [co][KP], k = tap*CIN+ci, linear ----------------
__global__ void prep_w(const float* __restrict__ w, ushort* __restrict__ dst, int CIN, int COUT, int KP){
  int idx = blockIdx.x * 256 + threadIdx.x;
  if (idx >= COUT * KP) return;
  int co = idx / KP, kl = idx % KP;
  int KT = 9 * CIN;
  ushort v = 0;
  if (kl < KT){
    int tap = kl / CIN, ci = kl % CIN;
    v = f2bu(w[(co * CIN + ci) * 9 + tap]);
  }
  dst[idx] = v;
}

// fc weight f32 -> bf16, linear [256][4096]
__global__ void prep_fcb(const float* __restrict__ w, ushort* __restrict__ wb){
  int idx = blockIdx.x * 256 + threadIdx.x;
  if (idx >= 256 * 4096) return;
  wb[idx] = f2bu(w[idx]);
}

// LSTM hh weights -> bf16 [l][j][128]; bsum[l][j] = bih+bhh
__global__ void prep_lstm_hh(const float* __restrict__ Whh, const float* __restrict__ bih,
                             const float* __restrict__ bhh, ushort* __restrict__ WhhB,
                             float* __restrict__ bsum){
  int idx = blockIdx.x * 256 + threadIdx.x;            // 5*512*128 = 327680
  if (idx < 327680) WhhB[idx] = f2bu(Whh[idx]);
  if (idx < 2560) bsum[idx] = bih[idx] + bhh[idx];
}

// ---------------- conv1: 1->32ch, stride 2, channels-last bf16 out, coalesced uint4 stores ----------------
__global__ __launch_bounds__(256) void conv1_gelu(const float* __restrict__ x, const float* __restrict__ w,
                                                  const float* __restrict__ b, ushort* __restrict__ out){
  __shared__ float sw[288];
  __shared__ float sb[32];
  int tid = threadIdx.x;
  if (tid < 288) sw[tid] = w[tid];
  if (tid < 32)  sb[tid] = b[tid];
  __syncthreads();
  int pl = tid >> 2, q = tid & 3;
  int gp = blockIdx.x * 64 + pl;
  int n = gp >> 10, p = gp & 1023;
  int oy = p >> 5, ox = p & 31;
  const float* xim = x + (size_t)n * 4096;
  float patch[9];
#pragma unroll
  for (int dy = 0; dy < 3; ++dy)
#pragma unroll
    for (int dx = 0; dx < 3; ++dx){
      int iy = oy * 2 + dy - 1, ix = ox * 2 + dx - 1;
      bool ok = ((unsigned)iy < 64u) && ((unsigned)ix < 64u);
      patch[dy * 3 + dx] = ok ? xim[iy * 64 + ix] : 0.f;
    }
  __align__(16) ushort res[8];
#pragma unroll
  for (int j = 0; j < 8; ++j){
    int co = q * 8 + j;
    float a = sb[co];
#pragma unroll
    for (int t = 0; t < 9; ++t) a = fmaf(patch[t], sw[co * 9 + t], a);
    res[j] = f2bu(gelu_exact(a));
  }
  *(uint4*)(out + (size_t)gp * 32 + q * 8) = *(const uint4*)res;
}

// ---------------- implicit-GEMM MFMA conv (3x3, pad 1), channels-last, padded LDS ----------------
template<int CIN, int COUT, int HOUT, int WOUT, int S, int WAVES, bool NCHW_OUT>
__global__ __launch_bounds__(WAVES * 64) void conv_mfma(const ushort* __restrict__ in, const ushort* __restrict__ wt,
                                                        const float* __restrict__ bias, ushort* __restrict__ out){
  constexpr int HIN = HOUT * S, WIN = WOUT * S;
  constexpr int KT = 9 * CIN;
  constexpr int KP = (CIN == 32) ? 296 : 600;
  constexpr int CP = CIN + 8;
  constexpr int PIN = HIN * WIN;
  constexpr int POUT = HOUT * WOUT;
  constexpr int MT = POUT / 16, NT = COUT / 16, MTW = MT / WAVES;
  constexpr int NTH = WAVES * 64;
  constexpr int KS = KT / 32;
  __shared__ __align__(16) ushort sIn[PIN * CP];
  __shared__ __align__(16) ushort sW[COUT * KP];
  int tid = threadIdx.x;

  const ushort* gin = in + (size_t)blockIdx.x * PIN * CIN;
  for (int t = tid; t < PIN * CIN / 8; t += NTH){
    int e = t * 8;
    int ci = e & (CIN - 1);
    int pix = e / CIN;
    *(uint4*)&sIn[pix * CP + ci] = *(const uint4*)(gin + e);
  }
  for (int t = tid; t < COUT * KP / 8; t += NTH)
    *(uint4*)&sW[t * 8] = *(const uint4*)(wt + t * 8);
  __syncthreads();

  int wid = tid >> 6, lane = tid & 63;
  int l15 = lane & 15, lg = lane >> 4;

  int iyb[MTW], ixb[MTW];
#pragma unroll
  for (int m = 0; m < MTW; ++m){
    int mt = m * WAVES + wid;
    int p = mt * 16 + l15;
    iyb[m] = (p / WOUT) * S - 1;
    ixb[m] = (p % WOUT) * S - 1;
  }
  f32x4 acc[MTW][NT] = {};
  float bv[NT];
#pragma unroll
  for (int nt = 0; nt < NT; ++nt) bv[nt] = bias[nt * 16 + l15];

  const bf16x8 ZV = {0,0,0,0,0,0,0,0};
#pragma unroll
  for (int ks = 0; ks < KS; ++ks){
    int tap = (ks * 32) / CIN;
    int dy = tap / 3, dx = tap % 3;
    int cib = (ks * 32) % CIN + lg * 8;
    bf16x8 bfr[NT];
#pragma unroll
    for (int nt = 0; nt < NT; ++nt){
      int co = nt * 16 + l15;
      bfr[nt] = *(const bf16x8*)&sW[co * KP + ks * 32 + lg * 8];
    }
#pragma unroll
    for (int m = 0; m < MTW; ++m){
      int iy = iyb[m] + dy, ix = ixb[m] + dx;
      bool ok = ((unsigned)iy < (unsigned)HIN) && ((unsigned)ix < (unsigned)WIN);
      int pixi = ok ? (iy * WIN + ix) : 0;
      bf16x8 a = *(const bf16x8*)&sIn[pixi * CP + cib];
      if (!ok) a = ZV;
#pragma unroll
      for (int nt = 0; nt < NT; ++nt)
        acc[m][nt] = __builtin_amdgcn_mfma_f32_16x16x32_bf16(a, bfr[nt], acc[m][nt], 0, 0, 0);
    }
  }

  if constexpr (!NCHW_OUT){
    constexpr int RG = 16 * WAVES;
    __shared__ ushort sOut[RG * COUT];
    size_t obase = (size_t)blockIdx.x * POUT * COUT;
#pragma unroll
    for (int m = 0; m < MTW; ++m){
      if (m) __syncthreads();
#pragma unroll
      for (int nt = 0; nt < NT; ++nt){
        int co = nt * 16 + l15;
#pragma unroll
        for (int r = 0; r < 4; ++r){
          int rl = wid * 16 + lg * 4 + r;
          sOut[rl * COUT + co] = f2bu(gelu_exact(acc[m][nt][r] + bv[nt]));
        }
      }
      __syncthreads();
      for (int t = tid; t < RG * COUT / 8; t += NTH)
        *(uint4*)(out + obase + (size_t)m * RG * COUT + t * 8) = *(const uint4*)&sOut[t * 8];
    }
  } else {
#pragma unroll
    for (int m = 0; m < MTW; ++m){
      int mt = m * WAVES + wid;
#pragma unroll
      for (int nt = 0; nt < NT; ++nt){
        int co = nt * 16 + l15;
#pragma unroll
        for (int r = 0; r < 4; ++r){
          int prow = mt * 16 + lg * 4 + r;
          float v = gelu_exact(acc[m][nt][r] + bv[nt]);
          out[(size_t)blockIdx.x * POUT * COUT + co * POUT + prow] = f2bu(v);
        }
      }
    }
  }
}

// ---------------- encoder FC, split-K MFMA: partial[sl][1040][256] (verified round 8) ----------------
__global__ __launch_bounds__(256) void fc_mfma_sk(const ushort* __restrict__ A, const ushort* __restrict__ Wb,
                                                  float* __restrict__ partial){
  __shared__ __align__(16) ushort sA[64][72];
  __shared__ __align__(16) ushort sB[256][72];
  int tid = threadIdx.x;
  int mt = blockIdx.x >> 3, sl = blockIdx.x & 7;
  int M0 = mt * 64;
  int wid = tid >> 6, lane = tid & 63;
  int l15 = lane & 15, lg = lane >> 4;

  f32x4 acc[16] = {};
  for (int i8 = 0; i8 < 8; ++i8){
    int kb = sl * 8 + i8;
#pragma unroll
    for (int i = 0; i < 2; ++i){
      int t = i * 256 + tid;
      int row = t >> 3, c = t & 7;
      int grow = M0 + row; if (grow > 1039) grow = 1039;
      *(uint4*)&sA[row][c * 8] = *(const uint4*)(A + (size_t)grow * 4096 + kb * 64 + c * 8);
    }
#pragma unroll
    for (int i = 0; i < 8; ++i){
      int t = i * 256 + tid;
      int row = t >> 3, c = t & 7;
      *(uint4*)&sB[row][c * 8] = *(const uint4*)(Wb + (size_t)row * 4096 + kb * 64 + c * 8);
    }
    __syncthreads();
#pragma unroll
    for (int ks = 0; ks < 2; ++ks){
      bf16x8 a = *(const bf16x8*)&sA[wid * 16 + l15][ks * 32 + lg * 8];
#pragma unroll
      for (int nt = 0; nt < 16; ++nt){
        bf16x8 b = *(const bf16x8*)&sB[nt * 16 + l15][ks * 32 + lg * 8];
        acc[nt] = __builtin_amdgcn_mfma_f32_16x16x32_bf16(a, b, acc[nt], 0, 0, 0);
      }
    }
    __syncthreads();
  }
#pragma unroll
  for (int nt = 0; nt < 16; ++nt){
    int j = nt * 16 + l15;
#pragma unroll
    for (int r = 0; r < 4; ++r){
      int row = M0 + wid * 16 + lg * 4 + r;
      if (row < 1040) partial[((size_t)sl * 1040 + row) * 256 + j] = acc[nt][r];
    }
  }
}

__global__ void fc_reduce(const float* __restrict__ partial, const float* __restrict__ fcb,
                          float* __restrict__ ml){
  int idx = blockIdx.x * 256 + threadIdx.x;
  if (idx >= 266240) return;
  float s = fcb[idx & 255];
#pragma unroll
  for (int q = 0; q < 8; ++q) s += partial[(size_t)q * 266240 + idx];
  ml[idx] = s;
}

// ---------------- reparameterization (+ f32 z relaid to [t*16+b][128]) ----------------
__global__ void reparam_kernel(const float* __restrict__ ml, float* __restrict__ z,
                               float* __restrict__ zre){
  int i = blockIdx.x * 256 + threadIdx.x;
  if (i >= 133120) return;
  uint32_t x0 = 0u, x1 = (uint32_t)i;
  threefry2x32(0u, 42u, x0, x1);
  uint32_t bits = x0 ^ x1;
  uint32_t fb = (bits >> 9) | 0x3f800000u;
  float f = __uint_as_float(fb) - 1.0f;
  const float lo = -0.99999994f;
  float u = f * 2.0f + lo;
  u = fmaxf(lo, u);
  float eps = 1.41421354f * erfinv_f(u);
  int n = i >> 7, d = i & 127;
  float ex = expf(fminf(0.5f * ml[n * 256 + 128 + d], 60.0f));
  float zv = fmaf(eps, ex, ml[n * 256 + d]);
  z[i] = zv;
  int b = n / 65, t = n - b * 65;
  if (t < 64) zre[((size_t)t * 16 + b) * 128 + d] = zv;
}

// ---------------- LSTM x-side GEMM, pure f32 VALU: xg[1024][512] = xin @ Wih^T + bsum ----------------
// 256 blocks x 512 threads; block = 4 rows, thread = one j column; W row cached in 128 VGPRs.
__global__ __launch_bounds__(512) void lstm_xg_f32(const float* __restrict__ xin,  // [1024][128]
                                                   const float* __restrict__ Wih,  // [512][128] f32
                                                   const float* __restrict__ bsum, // [512]
                                                   float* __restrict__ xg){        // [1024][512]
  int m0 = blockIdx.x * 4;
  int j = threadIdx.x;
  __shared__ float sX[4][128];
  sX[j >> 7][j & 127] = xin[(size_t)(m0 + (j >> 7)) * 128 + (j & 127)];
  __syncthreads();

  float w[128];
  const f32x4* wr = (const f32x4*)(Wih + (size_t)j * 128);
#pragma unroll
  for (int i = 0; i < 32; ++i){
    f32x4 v = wr[i];
    w[i * 4 + 0] = v[0]; w[i * 4 + 1] = v[1]; w[i * 4 + 2] = v[2]; w[i * 4 + 3] = v[3];
  }
  float bj = bsum[j];
#pragma unroll
  for (int r = 0; r < 4; ++r){
    float a0 = 0.f, a1 = 0.f, a2 = 0.f, a3 = 0.f;
#pragma unroll
    for (int kq = 0; kq < 32; ++kq){
      f32x4 xv = *(const f32x4*)&sX[r][kq * 4];
      a0 = fmaf(xv[0], w[kq * 4 + 0], a0);
      a1 = fmaf(xv[1], w[kq * 4 + 1], a1);
      a2 = fmaf(xv[2], w[kq * 4 + 2], a2);
      a3 = fmaf(xv[3], w[kq * 4 + 3], a3);
    }
    xg[(size_t)(m0 + r) * 512 + j] = ((a0 + a1) + (a2 + a3)) + bj;
  }
}

// ---------------- LSTM recurrence v2: 16 blocks (batch), 512 thr (gate-row j) ----------------
// hh-part only (xg precomputed); f32 h state; bf16 hh weights in 64 VGPRs; 4 indep chains.
__global__ __launch_bounds__(512) void lstm_rec2(const ushort* __restrict__ Whh,  // [512][128] bf16
                                                 const float* __restrict__ xg,    // [1024][512]
                                                 float* __restrict__ hout){       // [1024][128]
  int b = blockIdx.x;
  int tid = threadIdx.x;
  __shared__ float sH[128];
  __shared__ float gts[512];

  uint32_t whh[64];
  {
    const uint4* wp = (const uint4*)(Whh + (size_t)tid * 128);
#pragma unroll
    for (int i = 0; i < 16; ++i){
      uint4 v = wp[i];
      whh[i * 4 + 0] = v.x; whh[i * 4 + 1] = v.y; whh[i * 4 + 2] = v.z; whh[i * 4 + 3] = v.w;
    }
  }
  float c = 0.f;
  if (tid < 128) sH[tid] = 0.f;
  float xgv = xg[(size_t)b * 512 + tid];               // t = 0 (row t*16+b)
  __syncthreads();

  for (int t = 0; t < 64; ++t){
    float a0 = xgv, a1 = 0.f, a2 = 0.f, a3 = 0.f;
#pragma unroll
    for (int kc = 0; kc < 4; ++kc){                    // 32 k per group
      f32x4 hv[8];
#pragma unroll
      for (int q = 0; q < 8; ++q) hv[q] = *(const f32x4*)&sH[kc * 32 + q * 4];
#pragma unroll
      for (int q = 0; q < 8; ++q){
        uint32_t w0 = whh[kc * 16 + q * 2], w1 = whh[kc * 16 + q * 2 + 1];
        a0 = fmaf(hv[q][0], __uint_as_float(w0 << 16),         a0);
        a1 = fmaf(hv[q][1], __uint_as_float(w0 & 0xffff0000u), a1);
        a2 = fmaf(hv[q][2], __uint_as_float(w1 << 16),         a2);
        a3 = fmaf(hv[q][3], __uint_as_float(w1 & 0xffff0000u), a3);
      }
    }
    float xgn = 0.f;
    if (t < 63) xgn = xg[((size_t)(t + 1) * 16 + b) * 512 + tid];   // prefetch under barrier
    gts[tid] = (a0 + a1) + (a2 + a3);
    __syncthreads();                                   // gts ready; sH reads drained
    if (tid < 128){
      float gi = gts[tid], gf = gts[128 + tid], gg = gts[256 + tid], go = gts[384 + tid];
      float cn = sigmoidf_(gf) * c + sigmoidf_(gi) * tanhf(gg);
      float hn = sigmoidf_(go) * tanhf(cn);
      c = cn;
      sH[tid] = hn;
      hout[((size_t)t * 16 + b) * 128 + tid] = hn;
    }
    __syncthreads();                                   // sH ready for next step
    xgv = xgn;
  }
}

// ---------------- projection + MSE ----------------
__global__ void pred_loss(const float* __restrict__ hbuf, const float* __restrict__ lin_w,
                          const float* __restrict__ lin_b, const float* __restrict__ z,
                          float* __restrict__ partial){
  int blk = blockIdx.x;                                // 16*61
  int b = blk / 61, i = 3 + blk % 61;
  int tid = threadIdx.x;                               // 128
  __shared__ float h5[128];
  h5[tid] = hbuf[((size_t)(4 * 64 + i) * 16 + b) * 128 + tid];
  __syncthreads();
  float acc = lin_b[tid];
  const float* wr = lin_w + tid * 128;
#pragma unroll 8
  for (int k = 0; k < 128; ++k) acc = fmaf(h5[k], wr[k], acc);
  float zy = z[(b * 65 + i + 1) * 128 + tid];
  float df = acc - zy;
  float v = df * df;
  for (int off = 32; off > 0; off >>= 1) v += __shfl_down(v, off);
  __shared__ float wsum[2];
  if ((tid & 63) == 0) wsum[tid >> 6] = v;
  __syncthreads();
  if (tid == 0) partial[blk] = wsum[0] + wsum[1];
}

__global__ void loss_final(const float* __restrict__ partial, float* __restrict__ out){
  int tid = threadIdx.x;                               // 256
  float v = 0.0f;
  for (int i = tid; i < 976; i += 256) v += partial[i];
  for (int off = 32; off > 0; off >>= 1) v += __shfl_down(v, off);
  __shared__ float s[4];
  if ((tid & 63) == 0) s[tid >> 6] = v;
  __syncthreads();
  if (tid == 0) out[0] = (s[0] + s[1] + s[2] + s[3]) * (1.0f / 124928.0f);
}

extern "C" void kernel_launch(void* const* d_in, const int* in_sizes, int n_in,
                              void* d_out, int out_size, void* d_ws, size_t ws_size,
                              hipStream_t stream){
  const float* x   = (const float*)d_in[0];
  const float* ew1 = (const float*)d_in[1];  const float* eb1 = (const float*)d_in[2];
  const float* ew2 = (const float*)d_in[3];  const float* eb2 = (const float*)d_in[4];
  const float* ew3 = (const float*)d_in[5];  const float* eb3 = (const float*)d_in[6];
  const float* ew4 = (const float*)d_in[7];  const float* eb4 = (const float*)d_in[8];
  const float* ew5 = (const float*)d_in[9];  const float* eb5 = (const float*)d_in[10];
  const float* fcw = (const float*)d_in[11]; const float* fcb = (const float*)d_in[12];
  // d_in[13..24]: decoder params (dead code in the reference) — unused
  const float* Wih = (const float*)d_in[25]; const float* Whh = (const float*)d_in[26];
  const float* bih = (const float*)d_in[27]; const float* bhh = (const float*)d_in[28];
  const float* lw  = (const float*)d_in[29]; const float* lb  = (const float*)d_in[30];

  char* ws = (char*)d_ws;
  size_t off = 0;
  auto alloc = [&](size_t bytes) -> void* {
    void* p = ws + off;
    off = (off + bytes + 255) & ~(size_t)255;
    return p;
  };
  ushort* bufA  = (ushort*)alloc(34078720ull * 2);     // 1040*1024*32 bf16
  ushort* bufB  = (ushort*)alloc(34078720ull * 2);
  ushort* wt2   = (ushort*)alloc(32ull * 296 * 2);
  ushort* wt3   = (ushort*)alloc(64ull * 296 * 2);
  ushort* wt4   = (ushort*)alloc(64ull * 600 * 2);
  ushort* wt5   = (ushort*)alloc(64ull * 600 * 2);
  ushort* fcwB  = (ushort*)alloc(256ull * 4096 * 2);
  ushort* WhhB  = (ushort*)alloc(5ull * 512 * 128 * 2);
  float*  bsum  = (float*) alloc(5ull * 512 * 4);
  float*  ml    = (float*) alloc(1040ull * 256 * 4);
  float*  zbuf  = (float*) alloc(1040ull * 128 * 4);
  float*  zre   = (float*) alloc(1024ull * 128 * 4);
  float*  xgbuf = (float*) alloc(1024ull * 512 * 4);
  float*  hbuf  = (float*) alloc(5ull * 1024 * 128 * 4);
  float*  part  = (float*) alloc(976ull * 4);
  float*  fpart = (float*)bufB;                        // fc split-K partials reuse dead bufB

  prep_w<<<(32 * 296 + 255) / 256, 256, 0, stream>>>(ew2, wt2, 32, 32, 296);
  prep_w<<<(64 * 296 + 255) / 256, 256, 0, stream>>>(ew3, wt3, 32, 64, 296);
  prep_w<<<(64 * 600 + 255) / 256, 256, 0, stream>>>(ew4, wt4, 64, 64, 600);
  prep_w<<<(64 * 600 + 255) / 256, 256, 0, stream>>>(ew5, wt5, 64, 64, 600);
  prep_fcb<<<4096, 256, 0, stream>>>(fcw, fcwB);
  prep_lstm_hh<<<1280, 256, 0, stream>>>(Whh, bih, bhh, WhhB, bsum);

  conv1_gelu<<<16640, 256, 0, stream>>>(x, ew1, eb1, bufA);
  conv_mfma<32, 32, 32, 32, 1, 8, false><<<1040, 512, 0, stream>>>(bufA, wt2, eb2, bufB);
  conv_mfma<32, 64, 16, 16, 2, 8, false><<<1040, 512, 0, stream>>>(bufB, wt3, eb3, bufA);
  conv_mfma<64, 64, 16, 16, 1, 8, false><<<1040, 512, 0, stream>>>(bufA, wt4, eb4, bufB);
  conv_mfma<64, 64,  8,  8, 2, 4, true ><<<1040, 256, 0, stream>>>(bufB, wt5, eb5, bufA);

  fc_mfma_sk<<<136, 256, 0, stream>>>(bufA, fcwB, fpart);
  fc_reduce<<<1040, 256, 0, stream>>>(fpart, fcb, ml);
  reparam_kernel<<<(133120 + 255) / 256, 256, 0, stream>>>(ml, zbuf, zre);

  for (int l = 0; l < 5; ++l){
    const float* xin = (l == 0) ? zre : (hbuf + (size_t)(l - 1) * 131072);
    lstm_xg_f32<<<256, 512, 0, stream>>>(xin, Wih + (size_t)l * 65536, bsum + l * 512, xgbuf);
    lstm_rec2<<<16, 512, 0, stream>>>(WhhB + (size_t)l * 65536, xgbuf, hbuf + (size_t)l * 131072);
  }

  pred_loss<<<976, 128, 0, stream>>>(hbuf, lw, lb, zbuf, part);
  loss_final<<<1, 256, 0, stream>>>(part, (float*)d_out);
}